// Round 8
// baseline (8089.376 us; speedup 1.0000x reference)
//
#include <hip/hip_runtime.h>

#define N_PTS 16384
#define ROWF  131        // 3 coords + 128 features
#define M_OUT 4096       // N / POOL
#define KNN   16
#define FPS_T 1024       // fps threads (16 waves)
#define SORT_T 1024

typedef unsigned long long u64;

// spread 4 bits -> every 3rd bit (Morton interleave LUT)
__device__ __constant__ unsigned short c_spread4[16] =
  {0,1,8,9,64,65,72,73,512,513,520,521,576,577,584,585};

__device__ __forceinline__ int cell_of(float x, float y, float z) {
  int ix = (int)floorf((x + 4.0f) * 2.0f); ix = ix < 0 ? 0 : (ix > 15 ? 15 : ix);
  int iy = (int)floorf((y + 4.0f) * 2.0f); iy = iy < 0 ? 0 : (iy > 15 ? 15 : iy);
  int iz = (int)floorf((z + 4.0f) * 2.0f); iz = iz < 0 ? 0 : (iz > 15 ? 15 : iz);
  return (int)c_spread4[ix] | ((int)c_spread4[iy] << 1) | ((int)c_spread4[iz] << 2);
}

// ---------------------------------------------------------------------------
// 1) Extract coords into packed float4 (x,y,z,unused), orig-index order.
// ---------------------------------------------------------------------------
__global__ void prep_kernel(const float* __restrict__ x,
                            float4* __restrict__ coords4) {
  const int p = blockIdx.x * blockDim.x + threadIdx.x;
  if (p < N_PTS) {
    coords4[p] = make_float4(x[p * ROWF + 0], x[p * ROWF + 1],
                             x[p * ROWF + 2], 0.0f);
  }
}

// ---------------------------------------------------------------------------
// 2) Counting-sort by Morton cell (4096 cells), one 1024-thread block.
//    Output: slot-major packed float4 (x,y,z,bitcast(origIdx)):
//    sorted rank rk -> slot ((rk&15)<<10)|(rk>>4); fps thread t owns sorted
//    ranks [16t,16t+16) and loads gP4[(j<<10)+t] coalesced. A wave's 64
//    threads own 1024 CONSECUTIVE sorted ranks -> spatially compact region
//    for the wave-level prune. Within-cell scatter order racy but
//    output-invariant.
// ---------------------------------------------------------------------------
__global__ __launch_bounds__(1024, 1)
void sort_kernel(const float4* __restrict__ coords4, float4* __restrict__ gP4) {
  __shared__ unsigned int sh[4096];
  __shared__ unsigned int sws[16];
  const int tid = threadIdx.x, lane = tid & 63, wid = tid >> 6;

#pragma unroll
  for (int i = 0; i < 4; ++i) sh[tid * 4 + i] = 0;
  __syncthreads();

  int cel[16];
#pragma unroll
  for (int j = 0; j < 16; ++j) {
    const float4 v = coords4[tid + SORT_T * j];
    const int c = cell_of(v.x, v.y, v.z);
    cel[j] = c;
    atomicAdd(&sh[c], 1u);
  }
  __syncthreads();

  // prefix sum over 4096 counts (4 per thread)
  const unsigned h0 = sh[tid * 4 + 0], h1 = sh[tid * 4 + 1];
  const unsigned h2 = sh[tid * 4 + 2], h3 = sh[tid * 4 + 3];
  const unsigned tsum = h0 + h1 + h2 + h3;
  unsigned inc = tsum;
#pragma unroll
  for (int off = 1; off < 64; off <<= 1) {
    const unsigned v = __shfl_up(inc, off);
    if (lane >= off) inc += v;
  }
  if (lane == 63) sws[wid] = inc;
  __syncthreads();
  if (tid == 0) {
    unsigned run = 0;
#pragma unroll
    for (int w = 0; w < 16; ++w) { const unsigned t = sws[w]; sws[w] = run; run += t; }
  }
  __syncthreads();
  const unsigned base = sws[wid] + inc - tsum;
  sh[tid * 4 + 0] = base;
  sh[tid * 4 + 1] = base + h0;
  sh[tid * 4 + 2] = base + h0 + h1;
  sh[tid * 4 + 3] = base + h0 + h1 + h2;
  __syncthreads();

#pragma unroll
  for (int j = 0; j < 16; ++j) {
    const int p = tid + SORT_T * j;
    const float4 v = coords4[p];
    const unsigned rk = atomicAdd(&sh[cel[j]], 1u);
    const int slot = (int)(((rk & 15u) << 10) | (rk >> 4));
    gP4[slot] = make_float4(v.x, v.y, v.z, __int_as_float(p));
  }
}

// ---------------------------------------------------------------------------
// 3) FPS with WAVE-UNIFORM pruning. Round-7 counters (FETCH=407KB: no spill;
//    VALUBusy~52%/CU) showed the cost is the all-dirty VALU update + u64
//    butterfly every step: per-LANE prune saves nothing under the exec mask
//    (wave runs the body if ANY lane is dirty). Now each wave precomputes a
//    bounding sphere over its 1024 Morton-consecutive points; per step one
//    UNIFORM test (readfirstlane -> scalar branch) skips update AND
//    butterfly for the whole wave, reusing the cached wave-max key wk.
//    Skip => (dist(q,wc)-wr)^2 > max member md (with conservative margins)
//    => no member's fminf(md,d2) changes AND wk stays valid => trajectory
//    bitwise identical to the unpruned reference. The winner's wave always
//    fails the test (dd <= wr^2 < wu2), so its md -> 0 is tracked.
//    Key = (md_bits<<32) | (N-1-origIdx): max -> max md, tie -> lowest idx.
//    One barrier/step: s_wkey double-buffered by step parity.
// ---------------------------------------------------------------------------
#define REP16(F) F(0) F(1) F(2) F(3) F(4) F(5) F(6) F(7) \
                 F(8) F(9) F(10) F(11) F(12) F(13) F(14) F(15)

__global__
__attribute__((amdgpu_flat_work_group_size(FPS_T, FPS_T)))
__attribute__((amdgpu_waves_per_eu(4, 4)))
void fps_kernel(const float4* __restrict__ coords4,
                const float4* __restrict__ gP4, float* __restrict__ out) {
  __shared__ u64 s_wkey[2][16];
  const int tid = threadIdx.x, lane = tid & 63, wid = tid >> 6;

#define FPS_DECL(j) float px##j, py##j, pz##j, md##j; unsigned ni##j;
  REP16(FPS_DECL)
#undef FPS_DECL

#define FPS_INIT(j) { const float4 v = gP4[(j << 10) + tid];               \
    px##j = v.x; py##j = v.y; pz##j = v.z;                                 \
    ni##j = (unsigned)(N_PTS - 1 - __float_as_int(v.w));                   \
    md##j = __int_as_float(0x7f800000); }
  REP16(FPS_INIT)
#undef FPS_INIT

  // ---- wave bounding sphere over this wave's 1024 points
  float sx = 0.f, sy = 0.f, sz = 0.f;
#define FPS_ACC(j) sx += px##j; sy += py##j; sz += pz##j;
  REP16(FPS_ACC)
#undef FPS_ACC
#pragma unroll
  for (int off = 32; off; off >>= 1) {
    sx += __shfl_xor(sx, off);
    sy += __shfl_xor(sy, off);
    sz += __shfl_xor(sz, off);
  }
  const float wx = sx * (1.0f / 1024.0f), wy = sy * (1.0f / 1024.0f),
              wz = sz * (1.0f / 1024.0f);
  float wr2 = 0.f;
#define FPS_RAD(j) { const float dx = px##j - wx, dy = py##j - wy,         \
                     dz = pz##j - wz;                                      \
    wr2 = fmaxf(wr2, dx * dx + dy * dy + dz * dz); }
  REP16(FPS_RAD)
#undef FPS_RAD
#pragma unroll
  for (int off = 32; off; off >>= 1)
    wr2 = fmaxf(wr2, __shfl_xor(wr2, off));
  const float wr = sqrtf(wr2) * 1.000001f + 1e-6f;   // uniform

  float wu2 = __int_as_float(0x7f800000);  // wave prune threshold^2 (uniform)
  u64 wk = 0;                              // cached wave max key (uniform)

  const float4 q0 = coords4[0];
  float qx = q0.x, qy = q0.y, qz = q0.z;
  if (tid == 0) { out[0] = qx; out[1] = qy; out[2] = qz; }

  for (int s = 1; s < M_OUT; ++s) {
    // wave-uniform prune test (scalar branch via readfirstlane)
    const float ddx = wx - qx, ddy = wy - qy, ddz = wz - qz;
    const float dd = ddx * ddx + ddy * ddy + ddz * ddz;
    const int dirty = (dd * 0.999999f <= wu2) ? 1 : 0;

    if (__builtin_amdgcn_readfirstlane(dirty)) {
      u64 nk = 0;
#define FPS_UPD(j) {                                                       \
      const float dx = px##j - qx, dy = py##j - qy, dz = pz##j - qz;       \
      const float d2 = __fadd_rn(__fadd_rn(__fmul_rn(dx, dx),              \
                                           __fmul_rn(dy, dy)),             \
                                 __fmul_rn(dz, dz));                       \
      const float nm = fminf(md##j, d2);                                   \
      md##j = nm;                                                          \
      const u64 kj = ((u64)__float_as_uint(nm) << 32) | ni##j;             \
      nk = (kj > nk) ? kj : nk; }
      REP16(FPS_UPD)
#undef FPS_UPD
      // intra-wave butterfly -> wave max key (uniform), dirty waves only
#pragma unroll
      for (int off = 32; off; off >>= 1) {
        const u64 o = __shfl_xor(nk, off);
        if (o > nk) nk = o;
      }
      wk = nk;
      // rebuild wave prune threshold from new wave-max md (conservative)
      const float cmax = __uint_as_float((unsigned)(wk >> 32));
      const float u = (sqrtf(cmax * 1.0001f + 1e-12f) + wr) * 1.000003f;
      wu2 = u * u * 1.000001f;
    }

    const int par = s & 1;
    if (lane == 0) s_wkey[par][wid] = wk;
    __syncthreads();                             // the ONLY barrier per step
    u64 kk = s_wkey[par][lane & 15];
#pragma unroll
    for (int off = 8; off; off >>= 1) {
      const u64 o = __shfl_xor(kk, off);
      if (o > kk) kk = o;
    }
    const int oidx = (N_PTS - 1) - (int)(unsigned)kk;
    const float4 w = coords4[oidx];              // one uniform 16B load
    qx = w.x; qy = w.y; qz = w.z;
    if (tid == 0) {
      float* orow = out + (size_t)s * ROWF;
      orow[0] = qx; orow[1] = qy; orow[2] = qz;
    }
  }
}

// ---------------------------------------------------------------------------
// 4) KNN top-16 (ties -> lowest index) fused with feature max-pool.
//    One wave per query; query coords read from out rows (written by fps).
//    Packed u64 (d2_bits<<32 | idx) == lex (d2, idx).
// ---------------------------------------------------------------------------
__global__ __launch_bounds__(256)
void knn_pool_kernel(const float* __restrict__ x,
                     const float4* __restrict__ coords4,
                     float* __restrict__ out) {
  const int lane = threadIdx.x & 63;
  const int q = blockIdx.x * 4 + (threadIdx.x >> 6);

  const float qx = out[(size_t)q * ROWF + 0];
  const float qy = out[(size_t)q * ROWF + 1];
  const float qz = out[(size_t)q * ROWF + 2];

  u64 h[KNN];
#pragma unroll
  for (int k = 0; k < KNN; ++k) h[k] = ~0ULL;

  for (int c = lane; c < N_PTS; c += 64) {
    const float4 v = coords4[c];                 // coalesced 16B
    const float dx = v.x - qx, dy = v.y - qy, dz = v.z - qz;
    const float d2 = __fadd_rn(__fadd_rn(__fmul_rn(dx, dx), __fmul_rn(dy, dy)),
                               __fmul_rn(dz, dz));
    const u64 e = ((u64)__float_as_uint(d2) << 32) | (unsigned)c;
    if (e < h[KNN - 1]) {
#pragma unroll
      for (int k = KNN - 1; k >= 1; --k) {
        const u64 prev = h[k - 1];
        h[k] = (e < prev) ? prev : ((e < h[k]) ? e : h[k]);
      }
      h[0] = (e < h[0]) ? e : h[0];
    }
  }

  int nbr[KNN];
#pragma unroll
  for (int rr = 0; rr < KNN; ++rr) {
    u64 best = h[0];
#pragma unroll
    for (int off = 32; off; off >>= 1) {
      const u64 o = __shfl_xor(best, off);
      best = (o < best) ? o : best;
    }
    nbr[rr] = (int)(unsigned)(best & 0xffffffffULL);
    if (h[0] == best) {
#pragma unroll
      for (int k = 0; k < KNN - 1; ++k) h[k] = h[k + 1];
      h[KNN - 1] = ~0ULL;
    }
  }

  float a0 = __int_as_float(0xff800000), a1 = a0;
#pragma unroll
  for (int rr = 0; rr < KNN; ++rr) {
    const float* row = x + (size_t)nbr[rr] * ROWF + 3;
    a0 = fmaxf(a0, row[lane]);
    a1 = fmaxf(a1, row[lane + 64]);
  }
  float* orow = out + (size_t)q * ROWF + 3;
  orow[lane] = a0;
  orow[lane + 64] = a1;
}

extern "C" void kernel_launch(void* const* d_in, const int* in_sizes, int n_in,
                              void* d_out, int out_size, void* d_ws, size_t ws_size,
                              hipStream_t stream) {
  const float* x = (const float*)d_in[0];
  float* out = (float*)d_out;

  float4* coords4 = (float4*)d_ws;          // N float4 (256 KB)
  float4* gP4     = coords4 + N_PTS;        // N float4 (256 KB)

  hipLaunchKernelGGL(prep_kernel, dim3(64), dim3(256), 0, stream, x, coords4);
  hipLaunchKernelGGL(sort_kernel, dim3(1), dim3(1024), 0, stream, coords4, gP4);
  hipLaunchKernelGGL(fps_kernel, dim3(1), dim3(FPS_T), 0, stream,
                     coords4, gP4, out);
  hipLaunchKernelGGL(knn_pool_kernel, dim3(M_OUT / 4), dim3(256), 0, stream,
                     x, coords4, out);
}

// Round 9
// 7886.848 us; speedup vs baseline: 1.0257x; 1.0257x over previous
//
#include <hip/hip_runtime.h>

#define N_PTS 16384
#define ROWF  131        // 3 coords + 128 features
#define M_OUT 4096       // N / POOL
#define KNN   16
#define FPS_T 1024       // fps threads (16 waves)
#define SORT_T 1024

typedef unsigned long long u64;

// spread 4 bits -> every 3rd bit (Morton interleave LUT)
__device__ __constant__ unsigned short c_spread4[16] =
  {0,1,8,9,64,65,72,73,512,513,520,521,576,577,584,585};

__device__ __forceinline__ int cell_of(float x, float y, float z) {
  int ix = (int)floorf((x + 4.0f) * 2.0f); ix = ix < 0 ? 0 : (ix > 15 ? 15 : ix);
  int iy = (int)floorf((y + 4.0f) * 2.0f); iy = iy < 0 ? 0 : (iy > 15 ? 15 : iy);
  int iz = (int)floorf((z + 4.0f) * 2.0f); iz = iz < 0 ? 0 : (iz > 15 ? 15 : iz);
  return (int)c_spread4[ix] | ((int)c_spread4[iy] << 1) | ((int)c_spread4[iz] << 2);
}

// ---------------------------------------------------------------------------
// 1) Extract coords into packed float4 (x,y,z,unused), orig-index order.
// ---------------------------------------------------------------------------
__global__ void prep_kernel(const float* __restrict__ x,
                            float4* __restrict__ coords4) {
  const int p = blockIdx.x * blockDim.x + threadIdx.x;
  if (p < N_PTS) {
    coords4[p] = make_float4(x[p * ROWF + 0], x[p * ROWF + 1],
                             x[p * ROWF + 2], 0.0f);
  }
}

// ---------------------------------------------------------------------------
// 2) Counting-sort by Morton cell (4096 cells), one 1024-thread block.
//    Output: slot-major packed float4 (x,y,z,bitcast(origIdx)):
//    sorted rank rk -> slot ((rk&15)<<10)|(rk>>4); fps thread t owns sorted
//    ranks [16t,16t+16) (a spatially compact 16-point chunk) and loads
//    gP4[(j<<10)+t] coalesced. Within-cell scatter order racy but
//    output-invariant.
// ---------------------------------------------------------------------------
__global__ __launch_bounds__(1024, 1)
void sort_kernel(const float4* __restrict__ coords4, float4* __restrict__ gP4) {
  __shared__ unsigned int sh[4096];
  __shared__ unsigned int sws[16];
  const int tid = threadIdx.x, lane = tid & 63, wid = tid >> 6;

#pragma unroll
  for (int i = 0; i < 4; ++i) sh[tid * 4 + i] = 0;
  __syncthreads();

  int cel[16];
#pragma unroll
  for (int j = 0; j < 16; ++j) {
    const float4 v = coords4[tid + SORT_T * j];
    const int c = cell_of(v.x, v.y, v.z);
    cel[j] = c;
    atomicAdd(&sh[c], 1u);
  }
  __syncthreads();

  // prefix sum over 4096 counts (4 per thread)
  const unsigned h0 = sh[tid * 4 + 0], h1 = sh[tid * 4 + 1];
  const unsigned h2 = sh[tid * 4 + 2], h3 = sh[tid * 4 + 3];
  const unsigned tsum = h0 + h1 + h2 + h3;
  unsigned inc = tsum;
#pragma unroll
  for (int off = 1; off < 64; off <<= 1) {
    const unsigned v = __shfl_up(inc, off);
    if (lane >= off) inc += v;
  }
  if (lane == 63) sws[wid] = inc;
  __syncthreads();
  if (tid == 0) {
    unsigned run = 0;
#pragma unroll
    for (int w = 0; w < 16; ++w) { const unsigned t = sws[w]; sws[w] = run; run += t; }
  }
  __syncthreads();
  const unsigned base = sws[wid] + inc - tsum;
  sh[tid * 4 + 0] = base;
  sh[tid * 4 + 1] = base + h0;
  sh[tid * 4 + 2] = base + h0 + h1;
  sh[tid * 4 + 3] = base + h0 + h1 + h2;
  __syncthreads();

#pragma unroll
  for (int j = 0; j < 16; ++j) {
    const int p = tid + SORT_T * j;
    const float4 v = coords4[p];
    const unsigned rk = atomicAdd(&sh[cel[j]], 1u);
    const int slot = (int)(((rk & 15u) << 10) | (rk >> 4));
    gP4[slot] = make_float4(v.x, v.y, v.z, __int_as_float(p));
  }
}

// ---------------------------------------------------------------------------
// 3) FPS v9: f32 common path + deferred argmax + ballot chunk-prune.
//    Round-8 post-mortem: wave spheres never prune (Morton-tail radii),
//    and the u64 key fold + 64-bit butterfly were ~45% of issued ops.
//    Now: (a) per-lane fold & wave butterfly on f32 md only; (b) block max
//    via 16 f32 in LDS; (c) index resolution ONLY in wave(s) with
//    wavemax==blockmax: rescan regs for md==bm, min-ORIG-index butterfly,
//    per-wave slot + 16-way min (exact numpy first-index tie semantics);
//    (d) per-LANE 16-pt chunk spheres (tight, ~10x smaller than wave
//    spheres) + __ballot: wave skips update+butterfly only if ALL 64 chunk
//    tests pass. Conservative margins => skip provably leaves every
//    fminf(md,d2) a no-op => trajectory bitwise identical; winner's chunk
//    always dirty (dd<=cr^2<=thr); cached wm/thr stay valid on clean steps.
//    Named scalars (SROA-proof); waves_per_eu(4,4) keeps RA budget at 128.
// ---------------------------------------------------------------------------
#define REP16(F) F(0) F(1) F(2) F(3) F(4) F(5) F(6) F(7) \
                 F(8) F(9) F(10) F(11) F(12) F(13) F(14) F(15)

__global__
__attribute__((amdgpu_flat_work_group_size(FPS_T, FPS_T)))
__attribute__((amdgpu_waves_per_eu(4, 4)))
void fps_kernel(const float4* __restrict__ coords4,
                const float4* __restrict__ gP4, float* __restrict__ out) {
  __shared__ float    s_wmax[16];
  __shared__ unsigned s_warg[16];
  const int tid = threadIdx.x, lane = tid & 63, wid = tid >> 6;

#define FPS_DECL(j) float px##j, py##j, pz##j, md##j; unsigned ni##j;
  REP16(FPS_DECL)
#undef FPS_DECL

#define FPS_INIT(j) { const float4 v = gP4[(j << 10) + tid];               \
    px##j = v.x; py##j = v.y; pz##j = v.z;                                 \
    ni##j = (unsigned)__float_as_int(v.w);                                 \
    md##j = __int_as_float(0x7f800000); }
  REP16(FPS_INIT)
#undef FPS_INIT

  // ---- per-lane chunk bounding sphere over this lane's 16 compact points
  float sx = 0.f, sy = 0.f, sz = 0.f;
#define FPS_ACC(j) sx += px##j; sy += py##j; sz += pz##j;
  REP16(FPS_ACC)
#undef FPS_ACC
  const float ccx = sx * (1.0f / 16.0f), ccy = sy * (1.0f / 16.0f),
              ccz = sz * (1.0f / 16.0f);
  float cr2 = 0.f;
#define FPS_RAD(j) { const float dx = px##j - ccx, dy = py##j - ccy,       \
                     dz = pz##j - ccz;                                     \
    cr2 = fmaxf(cr2, dx * dx + dy * dy + dz * dz); }
  REP16(FPS_RAD)
#undef FPS_RAD
  const float cr = sqrtf(cr2) * 1.000001f + 1e-6f;

  float m   = __int_as_float(0x7f800000);  // lane chunk max md
  float thr = __int_as_float(0x7f800000);  // cached (cr+sqrt(m'))^2, +inf => dirty
  float wm  = __int_as_float(0x7f800000);  // cached wave max md (uniform)

  const float4 q0 = coords4[0];
  float qx = q0.x, qy = q0.y, qz = q0.z;
  if (tid == 0) { out[0] = qx; out[1] = qy; out[2] = qz; }

  for (int s = 1; s < M_OUT; ++s) {
    // ---- per-lane chunk prune test; wave updates iff ANY lane dirty
    const float dqx = qx - ccx, dqy = qy - ccy, dqz = qz - ccz;
    const float dd = dqx * dqx + dqy * dqy + dqz * dqz;
    const bool ldirty = (dd * 0.999999f <= thr);

    if (__ballot(ldirty)) {                      // wave-uniform branch
      float mn = 0.f;
#define FPS_UPD(j) {                                                       \
      const float dx = px##j - qx, dy = py##j - qy, dz = pz##j - qz;       \
      const float d2 = __fadd_rn(__fadd_rn(__fmul_rn(dx, dx),              \
                                           __fmul_rn(dy, dy)),             \
                                 __fmul_rn(dz, dz));                       \
      const float nm = fminf(md##j, d2);                                   \
      md##j = nm;                                                          \
      mn = fmaxf(mn, nm); }
      REP16(FPS_UPD)
#undef FPS_UPD
      m = mn;
      // f32 wave butterfly -> wave max md
      float t = m;
#pragma unroll
      for (int off = 32; off; off >>= 1)
        t = fmaxf(t, __shfl_xor(t, off));
      wm = t;
      // rebuild cached chunk prune threshold (conservative margins)
      const float u = (cr + sqrtf(m * 1.0001f)) * 1.000003f;
      thr = u * u * 1.000001f;
    }

    if (lane == 0) s_wmax[wid] = wm;
    __syncthreads();                             // barrier 1

    // block max of 16 wave maxes (values period-16 across lanes)
    float bmv = s_wmax[lane & 15];
#pragma unroll
    for (int off = 8; off; off >>= 1)
      bmv = fmaxf(bmv, __shfl_xor(bmv, off));

    // ---- deferred argmax: only wave(s) at the block max resolve the index
    unsigned cand = 0xFFFFFFFFu;
    if (wm == bmv) {                             // wave-uniform
      unsigned c = 0xFFFFFFFFu;
#define FPS_SCAN(j) c = (md##j == bmv) ? (ni##j < c ? ni##j : c) : c;
      REP16(FPS_SCAN)
#undef FPS_SCAN
#pragma unroll
      for (int off = 32; off; off >>= 1) {
        const unsigned o = __shfl_xor(c, off);
        c = (o < c) ? o : c;
      }
      cand = c;
    }
    if (lane == 0) s_warg[wid] = cand;
    __syncthreads();                             // barrier 2

    unsigned wv = s_warg[lane & 15];
#pragma unroll
    for (int off = 8; off; off >>= 1) {
      const unsigned o = __shfl_xor(wv, off);
      wv = (o < wv) ? o : wv;
    }
    const int oidx = (int)wv;                    // lowest orig idx at max
    const float4 wpt = coords4[oidx];            // uniform 16B load
    qx = wpt.x; qy = wpt.y; qz = wpt.z;
    if (tid == 0) {
      float* orow = out + (size_t)s * ROWF;
      orow[0] = qx; orow[1] = qy; orow[2] = qz;
    }
  }
}

// ---------------------------------------------------------------------------
// 4) KNN top-16 (ties -> lowest index) fused with feature max-pool.
//    One wave per query; query coords read from out rows (written by fps).
//    Packed u64 (d2_bits<<32 | idx) == lex (d2, idx).
// ---------------------------------------------------------------------------
__global__ __launch_bounds__(256)
void knn_pool_kernel(const float* __restrict__ x,
                     const float4* __restrict__ coords4,
                     float* __restrict__ out) {
  const int lane = threadIdx.x & 63;
  const int q = blockIdx.x * 4 + (threadIdx.x >> 6);

  const float qx = out[(size_t)q * ROWF + 0];
  const float qy = out[(size_t)q * ROWF + 1];
  const float qz = out[(size_t)q * ROWF + 2];

  u64 h[KNN];
#pragma unroll
  for (int k = 0; k < KNN; ++k) h[k] = ~0ULL;

  for (int c = lane; c < N_PTS; c += 64) {
    const float4 v = coords4[c];                 // coalesced 16B
    const float dx = v.x - qx, dy = v.y - qy, dz = v.z - qz;
    const float d2 = __fadd_rn(__fadd_rn(__fmul_rn(dx, dx), __fmul_rn(dy, dy)),
                               __fmul_rn(dz, dz));
    const u64 e = ((u64)__float_as_uint(d2) << 32) | (unsigned)c;
    if (e < h[KNN - 1]) {
#pragma unroll
      for (int k = KNN - 1; k >= 1; --k) {
        const u64 prev = h[k - 1];
        h[k] = (e < prev) ? prev : ((e < h[k]) ? e : h[k]);
      }
      h[0] = (e < h[0]) ? e : h[0];
    }
  }

  int nbr[KNN];
#pragma unroll
  for (int rr = 0; rr < KNN; ++rr) {
    u64 best = h[0];
#pragma unroll
    for (int off = 32; off; off >>= 1) {
      const u64 o = __shfl_xor(best, off);
      best = (o < best) ? o : best;
    }
    nbr[rr] = (int)(unsigned)(best & 0xffffffffULL);
    if (h[0] == best) {
#pragma unroll
      for (int k = 0; k < KNN - 1; ++k) h[k] = h[k + 1];
      h[KNN - 1] = ~0ULL;
    }
  }

  float a0 = __int_as_float(0xff800000), a1 = a0;
#pragma unroll
  for (int rr = 0; rr < KNN; ++rr) {
    const float* row = x + (size_t)nbr[rr] * ROWF + 3;
    a0 = fmaxf(a0, row[lane]);
    a1 = fmaxf(a1, row[lane + 64]);
  }
  float* orow = out + (size_t)q * ROWF + 3;
  orow[lane] = a0;
  orow[lane + 64] = a1;
}

extern "C" void kernel_launch(void* const* d_in, const int* in_sizes, int n_in,
                              void* d_out, int out_size, void* d_ws, size_t ws_size,
                              hipStream_t stream) {
  const float* x = (const float*)d_in[0];
  float* out = (float*)d_out;

  float4* coords4 = (float4*)d_ws;          // N float4 (256 KB)
  float4* gP4     = coords4 + N_PTS;        // N float4 (256 KB)

  hipLaunchKernelGGL(prep_kernel, dim3(64), dim3(256), 0, stream, x, coords4);
  hipLaunchKernelGGL(sort_kernel, dim3(1), dim3(1024), 0, stream, coords4, gP4);
  hipLaunchKernelGGL(fps_kernel, dim3(1), dim3(FPS_T), 0, stream,
                     coords4, gP4, out);
  hipLaunchKernelGGL(knn_pool_kernel, dim3(M_OUT / 4), dim3(256), 0, stream,
                     x, coords4, out);
}

// Round 10
// 6636.594 us; speedup vs baseline: 1.2189x; 1.1884x over previous
//
#include <hip/hip_runtime.h>

#define N_PTS 16384
#define ROWF  131        // 3 coords + 128 features
#define M_OUT 4096       // N / POOL
#define KNN   16
#define FPS_T 1024       // fps threads (16 waves)
#define SORT_T 1024

typedef unsigned long long u64;

// spread 4 bits -> every 3rd bit (Morton interleave LUT)
__device__ __constant__ unsigned short c_spread4[16] =
  {0,1,8,9,64,65,72,73,512,513,520,521,576,577,584,585};

__device__ __forceinline__ int cell_of(float x, float y, float z) {
  int ix = (int)floorf((x + 4.0f) * 2.0f); ix = ix < 0 ? 0 : (ix > 15 ? 15 : ix);
  int iy = (int)floorf((y + 4.0f) * 2.0f); iy = iy < 0 ? 0 : (iy > 15 ? 15 : iy);
  int iz = (int)floorf((z + 4.0f) * 2.0f); iz = iz < 0 ? 0 : (iz > 15 ? 15 : iz);
  return (int)c_spread4[ix] | ((int)c_spread4[iy] << 1) | ((int)c_spread4[iz] << 2);
}

// u64 max-combine with a DPP-moved partner (VALU-speed cross-lane, no DS pipe).
// Lanes outside ROW_MASK keep their old value (update_dpp 'old' operand).
template <int CTRL, int ROW_MASK>
__device__ __forceinline__ u64 kmax_dpp(u64 k) {
  const int lo = (int)(unsigned)k, hi = (int)(unsigned)(k >> 32);
  const int nlo = __builtin_amdgcn_update_dpp(lo, lo, CTRL, ROW_MASK, 0xf, false);
  const int nhi = __builtin_amdgcn_update_dpp(hi, hi, CTRL, ROW_MASK, 0xf, false);
  const u64 nk = ((u64)(unsigned)nhi << 32) | (unsigned)nlo;
  return nk > k ? nk : k;
}

// ---------------------------------------------------------------------------
// 1) Extract coords into packed float4 (x,y,z,unused), orig-index order.
// ---------------------------------------------------------------------------
__global__ void prep_kernel(const float* __restrict__ x,
                            float4* __restrict__ coords4) {
  const int p = blockIdx.x * blockDim.x + threadIdx.x;
  if (p < N_PTS) {
    coords4[p] = make_float4(x[p * ROWF + 0], x[p * ROWF + 1],
                             x[p * ROWF + 2], 0.0f);
  }
}

// ---------------------------------------------------------------------------
// 2) Counting-sort by Morton cell (4096 cells), one 1024-thread block.
//    slot-major packed float4 (x,y,z,bitcast(origIdx)); within-cell scatter
//    order racy but output-invariant.
// ---------------------------------------------------------------------------
__global__ __launch_bounds__(1024, 1)
void sort_kernel(const float4* __restrict__ coords4, float4* __restrict__ gP4) {
  __shared__ unsigned int sh[4096];
  __shared__ unsigned int sws[16];
  const int tid = threadIdx.x, lane = tid & 63, wid = tid >> 6;

#pragma unroll
  for (int i = 0; i < 4; ++i) sh[tid * 4 + i] = 0;
  __syncthreads();

  int cel[16];
#pragma unroll
  for (int j = 0; j < 16; ++j) {
    const float4 v = coords4[tid + SORT_T * j];
    const int c = cell_of(v.x, v.y, v.z);
    cel[j] = c;
    atomicAdd(&sh[c], 1u);
  }
  __syncthreads();

  const unsigned h0 = sh[tid * 4 + 0], h1 = sh[tid * 4 + 1];
  const unsigned h2 = sh[tid * 4 + 2], h3 = sh[tid * 4 + 3];
  const unsigned tsum = h0 + h1 + h2 + h3;
  unsigned inc = tsum;
#pragma unroll
  for (int off = 1; off < 64; off <<= 1) {
    const unsigned v = __shfl_up(inc, off);
    if (lane >= off) inc += v;
  }
  if (lane == 63) sws[wid] = inc;
  __syncthreads();
  if (tid == 0) {
    unsigned run = 0;
#pragma unroll
    for (int w = 0; w < 16; ++w) { const unsigned t = sws[w]; sws[w] = run; run += t; }
  }
  __syncthreads();
  const unsigned base = sws[wid] + inc - tsum;
  sh[tid * 4 + 0] = base;
  sh[tid * 4 + 1] = base + h0;
  sh[tid * 4 + 2] = base + h0 + h1;
  sh[tid * 4 + 3] = base + h0 + h1 + h2;
  __syncthreads();

#pragma unroll
  for (int j = 0; j < 16; ++j) {
    const int p = tid + SORT_T * j;
    const float4 v = coords4[p];
    const unsigned rk = atomicAdd(&sh[cel[j]], 1u);
    const int slot = (int)(((rk & 15u) << 10) | (rk >> 4));
    gP4[slot] = make_float4(v.x, v.y, v.z, __int_as_float(p));
  }
}

// ---------------------------------------------------------------------------
// 3) FPS v10: DPP reductions + single barrier + ballot chunk-prune.
//    Wave u64 max via 6 DPP levels (VALU pipe, not 50-cyc ds_bpermute);
//    cross-wave via one ds_read_b64 + 4 DPP levels, parity-buffered s_wkey,
//    ONE barrier/step. Dirty update folds f32 md-max (11 ops/pt); exact tie
//    index via 16-reg predicated post-scan (min orig idx among md==m);
//    key=(m_bits<<32)|(16383-c). Per-lane chunk spheres + ballot skip with
//    the same conservative margins as rounds 4-9 (skip => provably every
//    fminf(md,d2) is a no-op => bitwise-identical trajectory; absmax==0).
// ---------------------------------------------------------------------------
#define REP16(F) F(0) F(1) F(2) F(3) F(4) F(5) F(6) F(7) \
                 F(8) F(9) F(10) F(11) F(12) F(13) F(14) F(15)

__global__
__attribute__((amdgpu_flat_work_group_size(FPS_T, FPS_T)))
__attribute__((amdgpu_waves_per_eu(4, 4)))
void fps_kernel(const float4* __restrict__ coords4,
                const float4* __restrict__ gP4, float* __restrict__ out) {
  __shared__ u64 s_wkey[2][16];
  const int tid = threadIdx.x, lane = tid & 63, wid = tid >> 6;

#define FPS_DECL(j) float px##j, py##j, pz##j, md##j; unsigned ni##j;
  REP16(FPS_DECL)
#undef FPS_DECL

#define FPS_INIT(j) { const float4 v = gP4[(j << 10) + tid];               \
    px##j = v.x; py##j = v.y; pz##j = v.z;                                 \
    ni##j = (unsigned)__float_as_int(v.w);                                 \
    md##j = __int_as_float(0x7f800000); }
  REP16(FPS_INIT)
#undef FPS_INIT

  // per-lane chunk bounding sphere over this lane's 16 compact points
  float sx = 0.f, sy = 0.f, sz = 0.f;
#define FPS_ACC(j) sx += px##j; sy += py##j; sz += pz##j;
  REP16(FPS_ACC)
#undef FPS_ACC
  const float ccx = sx * (1.0f / 16.0f), ccy = sy * (1.0f / 16.0f),
              ccz = sz * (1.0f / 16.0f);
  float cr2 = 0.f;
#define FPS_RAD(j) { const float dx = px##j - ccx, dy = py##j - ccy,       \
                     dz = pz##j - ccz;                                     \
    cr2 = fmaxf(cr2, dx * dx + dy * dy + dz * dz); }
  REP16(FPS_RAD)
#undef FPS_RAD
  const float cr = sqrtf(cr2) * 1.000001f + 1e-6f;

  float thr = __int_as_float(0x7f800000);  // cached (cr+sqrt(m*1.0001))^2; +inf => dirty
  u64 wk = 0;                              // cached wave max key (uniform)

  const float4 q0 = coords4[0];
  float qx = q0.x, qy = q0.y, qz = q0.z;
  if (tid == 0) { out[0] = qx; out[1] = qy; out[2] = qz; }

  for (int s = 1; s < M_OUT; ++s) {
    // per-lane chunk prune test; wave updates iff ANY lane dirty
    const float dqx = qx - ccx, dqy = qy - ccy, dqz = qz - ccz;
    const float dd = dqx * dqx + dqy * dqy + dqz * dqz;
    const bool ldirty = (dd * 0.999999f <= thr);

    if (__ballot(ldirty)) {                      // wave-uniform branch
      float m = 0.f;
#define FPS_UPD(j) {                                                       \
      const float dx = px##j - qx, dy = py##j - qy, dz = pz##j - qz;       \
      const float d2 = __fadd_rn(__fadd_rn(__fmul_rn(dx, dx),              \
                                           __fmul_rn(dy, dy)),             \
                                 __fmul_rn(dz, dz));                       \
      const float nm = fminf(md##j, d2);                                   \
      md##j = nm;                                                          \
      m = fmaxf(m, nm); }
      REP16(FPS_UPD)
#undef FPS_UPD
      // exact tie index: min orig idx among this lane's md==m
      unsigned c = 0xFFFFFFFFu;
#define FPS_SCAN(j) c = (md##j == m) ? (ni##j < c ? ni##j : c) : c;
      REP16(FPS_SCAN)
#undef FPS_SCAN
      u64 k = ((u64)__float_as_uint(m) << 32) | (unsigned)(N_PTS - 1 - c);

      // wave max via DPP: 4 xor-style + 2 bcast levels; lanes 32-63 -> full
      k = kmax_dpp<0xB1,  0xf>(k);   // quad_perm [1,0,3,2]
      k = kmax_dpp<0x4E,  0xf>(k);   // quad_perm [2,3,0,1]
      k = kmax_dpp<0x141, 0xf>(k);   // row_half_mirror (8-group)
      k = kmax_dpp<0x140, 0xf>(k);   // row_mirror      (16-group)
      k = kmax_dpp<0x142, 0xa>(k);   // row_bcast15 -> rows 1,3 (32-group)
      k = kmax_dpp<0x143, 0xc>(k);   // row_bcast31 -> rows 2,3 (64-group)
      const unsigned wlo = (unsigned)__builtin_amdgcn_readlane((int)(unsigned)k, 63);
      const unsigned whi = (unsigned)__builtin_amdgcn_readlane((int)(unsigned)(k >> 32), 63);
      wk = ((u64)whi << 32) | wlo;               // uniform across wave

      // rebuild cached chunk prune threshold from LANE's chunk max m
      const float u = (cr + sqrtf(m * 1.0001f)) * 1.000003f;
      thr = u * u * 1.000001f;
    }

    const int par = s & 1;
    if (lane == 0) s_wkey[par][wid] = wk;
    __syncthreads();                             // the ONLY barrier per step
    u64 kk = s_wkey[par][lane & 15];
    kk = kmax_dpp<0xB1,  0xf>(kk);
    kk = kmax_dpp<0x4E,  0xf>(kk);
    kk = kmax_dpp<0x141, 0xf>(kk);
    kk = kmax_dpp<0x140, 0xf>(kk);               // all lanes: block max

    const int oidx = (N_PTS - 1) - (int)(unsigned)(kk & 0xFFFFFFFFu);
    const float4 wpt = coords4[oidx];            // one uniform 16B load
    qx = wpt.x; qy = wpt.y; qz = wpt.z;
    if (tid == 0) {
      float* orow = out + (size_t)s * ROWF;
      orow[0] = qx; orow[1] = qy; orow[2] = qz;
    }
  }
}

// ---------------------------------------------------------------------------
// 4) KNN top-16 (ties -> lowest index) fused with feature max-pool.
// ---------------------------------------------------------------------------
__global__ __launch_bounds__(256)
void knn_pool_kernel(const float* __restrict__ x,
                     const float4* __restrict__ coords4,
                     float* __restrict__ out) {
  const int lane = threadIdx.x & 63;
  const int q = blockIdx.x * 4 + (threadIdx.x >> 6);

  const float qx = out[(size_t)q * ROWF + 0];
  const float qy = out[(size_t)q * ROWF + 1];
  const float qz = out[(size_t)q * ROWF + 2];

  u64 h[KNN];
#pragma unroll
  for (int k = 0; k < KNN; ++k) h[k] = ~0ULL;

  for (int c = lane; c < N_PTS; c += 64) {
    const float4 v = coords4[c];                 // coalesced 16B
    const float dx = v.x - qx, dy = v.y - qy, dz = v.z - qz;
    const float d2 = __fadd_rn(__fadd_rn(__fmul_rn(dx, dx), __fmul_rn(dy, dy)),
                               __fmul_rn(dz, dz));
    const u64 e = ((u64)__float_as_uint(d2) << 32) | (unsigned)c;
    if (e < h[KNN - 1]) {
#pragma unroll
      for (int k = KNN - 1; k >= 1; --k) {
        const u64 prev = h[k - 1];
        h[k] = (e < prev) ? prev : ((e < h[k]) ? e : h[k]);
      }
      h[0] = (e < h[0]) ? e : h[0];
    }
  }

  int nbr[KNN];
#pragma unroll
  for (int rr = 0; rr < KNN; ++rr) {
    u64 best = h[0];
#pragma unroll
    for (int off = 32; off; off >>= 1) {
      const u64 o = __shfl_xor(best, off);
      best = (o < best) ? o : best;
    }
    nbr[rr] = (int)(unsigned)(best & 0xffffffffULL);
    if (h[0] == best) {
#pragma unroll
      for (int k = 0; k < KNN - 1; ++k) h[k] = h[k + 1];
      h[KNN - 1] = ~0ULL;
    }
  }

  float a0 = __int_as_float(0xff800000), a1 = a0;
#pragma unroll
  for (int rr = 0; rr < KNN; ++rr) {
    const float* row = x + (size_t)nbr[rr] * ROWF + 3;
    a0 = fmaxf(a0, row[lane]);
    a1 = fmaxf(a1, row[lane + 64]);
  }
  float* orow = out + (size_t)q * ROWF + 3;
  orow[lane] = a0;
  orow[lane + 64] = a1;
}

extern "C" void kernel_launch(void* const* d_in, const int* in_sizes, int n_in,
                              void* d_out, int out_size, void* d_ws, size_t ws_size,
                              hipStream_t stream) {
  const float* x = (const float*)d_in[0];
  float* out = (float*)d_out;

  float4* coords4 = (float4*)d_ws;          // N float4 (256 KB)
  float4* gP4     = coords4 + N_PTS;        // N float4 (256 KB)

  hipLaunchKernelGGL(prep_kernel, dim3(64), dim3(256), 0, stream, x, coords4);
  hipLaunchKernelGGL(sort_kernel, dim3(1), dim3(1024), 0, stream, coords4, gP4);
  hipLaunchKernelGGL(fps_kernel, dim3(1), dim3(FPS_T), 0, stream,
                     coords4, gP4, out);
  hipLaunchKernelGGL(knn_pool_kernel, dim3(M_OUT / 4), dim3(256), 0, stream,
                     x, coords4, out);
}